// Round 6
// baseline (382.196 us; speedup 1.0000x reference)
//
#include <hip/hip_runtime.h>
#include <float.h>
#include <stdint.h>

#define B_      64
#define TTXT    64
#define TIMG    197
#define DDIM    768
#define MT      63
#define NI      196
#define NPAD    224
#define DC      16
#define MARGIN_ 0.5f
#define EPS_    1e-6f

// ---- ws byte offsets ----
#define META_OFF   0u          // int meta[16]; meta[0] = R
#define NV_OFF     64u         // int nv[64]
#define ROWSRC_OFF 320u        // int rowsrc[4096]
#define ROWX_OFF   16704u      // int rowx[4096]
#define T2I_OFF    33088u      // float t2i_sum[4096]
#define I2T_OFF    49472u      // uint i2t_part[64*64*196]
// A image: [4096 rows][24 chunks][8 slots][16B] (3072 B/row), swizzle baked
#define AIMG_OFF   3260736u
// B image: [64*224 rows][24 chunks][8 slots][16B]
#define BIMG_OFF   15843648u
#define WS_NEEDED  59883840u

typedef _Float16 f16x8 __attribute__((ext_vector_type(8)));
typedef float    f32x4 __attribute__((ext_vector_type(4)));

__device__ __forceinline__ unsigned mono_map(float v) {
    unsigned b = __float_as_uint(v);
    return (b & 0x80000000u) ? ~b : (b | 0x80000000u);
}
__device__ __forceinline__ float mono_unmap(unsigned u) {
    unsigned b = (u & 0x80000000u) ? (u & 0x7fffffffu) : ~u;
    return __uint_as_float(b);
}

__device__ __forceinline__ void async_ld16(const void* g, void* l) {
    __builtin_amdgcn_global_load_lds((const __attribute__((address_space(1))) void*)g,
                                     (__attribute__((address_space(3))) void*)l,
                                     16, 0, 0);
}

// ================= FAST PATH =================

__global__ __launch_bounds__(64) void prep_kernel(const int* __restrict__ pm,
                                                  char* __restrict__ ws,
                                                  float* __restrict__ out) {
    int x = threadIdx.x;
    if (x == 0) out[0] = 0.f;                 // fin accumulates via atomics
    int* meta   = (int*)(ws + META_OFF);
    int* nv     = (int*)(ws + NV_OFF);
    int* rowsrc = (int*)(ws + ROWSRC_OFF);
    int* rowx   = (int*)(ws + ROWX_OFF);
    const int* row = pm + x * TTXT;
    int lastz = -1;
    for (int t = 0; t < TTXT; ++t) if (row[t] == 0) lastz = t;
    int eos = (lastz >= 0) ? lastz : 0;
    int cnt = 0; int loc[63];
    for (int t = 1; t < TTXT; ++t) {
        int v = row[t]; if (t == eos) v = 1;
        if (v == 0) loc[cnt++] = t;
    }
    int s = cnt;
    for (int d = 1; d < 64; d <<= 1) { int o = __shfl_up(s, d); if (x >= d) s += o; }
    int off = s - cnt;
    for (int j = 0; j < cnt; ++j) {
        rowsrc[off + j] = (x * TTXT + loc[j]) * DDIM;
        rowx[off + j] = x;
    }
    nv[x] = cnt;
    if (x == 63) meta[0] = off + cnt;    // R
}

// conv: swizzled hi/lo chunk images + init of reduction buffers.
// thread = (row, kc, group g) reads its 32B source ONCE, emits hi-slot and
// lo-slot (both land in the same 128B chunk line). image slot s holds source
// slot sp = s ^ (row&7); so dest s_h = g ^ rs, s_l = (g|4) ^ rs.
// grid 7697: [0,1536) A, [1536,6912) B, [6912,7696) i2t init, 7696 t2i init
__global__ __launch_bounds__(256) void conv_kernel(const float* __restrict__ img,
                                                   const float* __restrict__ txt,
                                                   char* __restrict__ ws) {
    const int bid = blockIdx.x, tid = threadIdx.x;
    if (bid < 1536) {                              // ---- A: 4096 rows x 24 kc x 4 groups
        int gid = bid * 256 + tid;
        int g  = gid & 3;
        int kc = (gid >> 2) % 24;
        int gr = gid / 96;
        const int R = *(const int*)(ws + META_OFF);
        f16x8 hv = 0, lv = 0;
        if (gr < R) {
            const int* rowsrc = (const int*)(ws + ROWSRC_OFF);
            const float* src = txt + rowsrc[gr] + kc * 32 + g * 8;
            float4 f0 = ((const float4*)src)[0];
            float4 f1 = ((const float4*)src)[1];
            float fv[8] = {f0.x, f0.y, f0.z, f0.w, f1.x, f1.y, f1.z, f1.w};
            #pragma unroll
            for (int j = 0; j < 8; ++j) {
                float fx = fv[j];
                _Float16 hh = (_Float16)fx;
                hv[j] = hh;
                lv[j] = (_Float16)(fx - (float)hh);
            }
        }
        int rs = gr & 7;
        char* base = ws + AIMG_OFF + (size_t)gr * 3072 + kc * 128;
        *(f16x8*)(base + ((g ^ rs) << 4))       = hv;
        *(f16x8*)(base + (((g | 4) ^ rs) << 4)) = lv;
    } else if (bid < 6912) {                       // ---- B: 14336 rows x 24 kc x 4 groups
        int gid = (bid - 1536) * 256 + tid;
        int g  = gid & 3;
        int kc = (gid >> 2) % 24;
        int rr = gid / 96;
        int y = rr / NPAD, i = rr % NPAD;
        f16x8 hv = 0, lv = 0;
        if (i < NI) {
            const float* src = img + (size_t)(y * TIMG + i + 1) * DDIM + kc * 32 + g * 8;
            float4 f0 = ((const float4*)src)[0];
            float4 f1 = ((const float4*)src)[1];
            float fv[8] = {f0.x, f0.y, f0.z, f0.w, f1.x, f1.y, f1.z, f1.w};
            #pragma unroll
            for (int j = 0; j < 8; ++j) {
                float fx = fv[j];
                _Float16 hh = (_Float16)fx;
                hv[j] = hh;
                lv[j] = (_Float16)(fx - (float)hh);
            }
        }
        int rs = rr & 7;                           // NPAD%8==0 -> rr&7 == i&7
        char* base = ws + BIMG_OFF + (size_t)rr * 3072 + kc * 128;
        *(f16x8*)(base + ((g ^ rs) << 4))       = hv;
        *(f16x8*)(base + (((g | 4) ^ rs) << 4)) = lv;
    } else if (bid < 7696) {                       // ---- i2t init (200704 uint4)
        int gid = (bid - 6912) * 256 + tid;
        uint4 v = make_uint4(0x00800000u, 0x00800000u, 0x00800000u, 0x00800000u);
        ((uint4*)(ws + I2T_OFF))[gid] = v;         // mono(-FLT_MAX)
    } else {                                       // ---- t2i init (1024 uint4)
        uint4 z = make_uint4(0u, 0u, 0u, 0u);
        #pragma unroll
        for (int j = 0; j < 4; ++j)
            ((uint4*)(ws + T2I_OFF))[tid * 4 + j] = z;
    }
}

// gemm: grid 1024 = 16 m-tiles(256) x 64 y; 256 threads = 4 waves (2x2),
// wave tile 128x112 (acc[8][7]) -> LDS reads per CU-chunk cut 176->120 b128.
// merged 3-pass (hh, hl, lh), double-buffered LDS, global_load_lds staging,
// 2-phase pipeline: prefetch chunk k+1 issued before compute of chunk k.
__global__ __launch_bounds__(256, 1) void gemm_kernel(char* __restrict__ ws) {
    const int bid = blockIdx.x;
    const int swz = (bid & 7) * 128 + (bid >> 3);   // XCD-chunked, bijective (1024%8==0)
    const int mt  = swz & 15;
    const int y   = swz >> 4;
    const int R = *(const int*)(ws + META_OFF);
    const int m_base = mt * 256;
    if (m_base >= R) return;

    const int tid = threadIdx.x;
    const int wid = tid >> 6, lane = tid & 63;
    const int c = lane & 15, g = lane >> 4;
    const int wm = wid >> 1, wn = wid & 1;

    __shared__ __align__(16) unsigned char lds[122880];  // 2 x (A 32K + B 28K)

    f32x4 acc[8][7];
    #pragma unroll
    for (int m = 0; m < 8; ++m)
        #pragma unroll
        for (int n = 0; n < 7; ++n) acc[m][n] = 0.f;

    const char* Abp = ws + AIMG_OFF + (size_t)m_base * 3072;
    const char* Bbp = ws + BIMG_OFF + (size_t)(y * NPAD) * 3072;
    int agoff[8], bgoff[7];
    #pragma unroll
    for (int i = 0; i < 8; ++i) { int u = i * 256 + tid; agoff[i] = (u >> 3) * 3072 + (u & 7) * 16; }
    #pragma unroll
    for (int i = 0; i < 7; ++i) { int u = i * 256 + tid; bgoff[i] = (u >> 3) * 3072 + (u & 7) * 16; }

    auto STAGE = [&](int buf, int kc) {
        unsigned char* base = lds + buf * 61440;
        const int ko = kc * 128;
        #pragma unroll
        for (int i = 0; i < 8; ++i)
            async_ld16(Abp + agoff[i] + ko, base + i * 4096 + wid * 1024);
        #pragma unroll
        for (int i = 0; i < 7; ++i)
            async_ld16(Bbp + bgoff[i] + ko, base + 32768 + i * 4096 + wid * 1024);
    };

    int aofh[8], aofl[8], bofh[7], bofl[7];
    #pragma unroll
    for (int m = 0; m < 8; ++m) {
        int r = wm * 128 + m * 16 + c;
        aofh[m] = r * 128 + ((g ^ (r & 7)) << 4);
        aofl[m] = r * 128 + (((4 | g) ^ (r & 7)) << 4);
    }
    #pragma unroll
    for (int n = 0; n < 7; ++n) {
        int i = wn * 112 + n * 16 + c;
        bofh[n] = 32768 + i * 128 + ((g ^ (i & 7)) << 4);
        bofl[n] = 32768 + i * 128 + (((4 | g) ^ (i & 7)) << 4);
    }

    STAGE(0, 0);
    __syncthreads();

    #pragma unroll 2
    for (int kc = 0; kc < 24; ++kc) {
        const int cur = kc & 1;
        if (kc < 23) STAGE(cur ^ 1, kc + 1);         // prefetch next chunk (in flight)
        const unsigned char* Ab = lds + cur * 61440;
        f16x8 ah[8], bh[7];
        #pragma unroll
        for (int m = 0; m < 8; ++m) ah[m] = *(const f16x8*)(Ab + aofh[m]);
        #pragma unroll
        for (int n = 0; n < 7; ++n) bh[n] = *(const f16x8*)(Ab + bofh[n]);
        #pragma unroll
        for (int m = 0; m < 8; ++m)
            #pragma unroll
            for (int n = 0; n < 7; ++n)
                acc[m][n] = __builtin_amdgcn_mfma_f32_16x16x32_f16(ah[m], bh[n], acc[m][n], 0, 0, 0);
        {   // hi * lo  (ah live, bl fresh)
            f16x8 bl[7];
            #pragma unroll
            for (int n = 0; n < 7; ++n) bl[n] = *(const f16x8*)(Ab + bofl[n]);
            #pragma unroll
            for (int m = 0; m < 8; ++m)
                #pragma unroll
                for (int n = 0; n < 7; ++n)
                    acc[m][n] = __builtin_amdgcn_mfma_f32_16x16x32_f16(ah[m], bl[n], acc[m][n], 0, 0, 0);
        }
        {   // lo * hi  (bh live, al fresh)
            f16x8 al[8];
            #pragma unroll
            for (int m = 0; m < 8; ++m) al[m] = *(const f16x8*)(Ab + aofl[m]);
            #pragma unroll
            for (int m = 0; m < 8; ++m)
                #pragma unroll
                for (int n = 0; n < 7; ++n)
                    acc[m][n] = __builtin_amdgcn_mfma_f32_16x16x32_f16(al[m], bh[n], acc[m][n], 0, 0, 0);
        }
        __syncthreads();
    }

    // ---- epilogue ----
    float* rowmax2 = (float*)lds;            // [2][256]
    int*   rowxl   = (int*)(lds + 2048);     // [256]
    const int* rowx = (const int*)(ws + ROWX_OFF);
    if (tid < 256) {
        int gr = m_base + tid;
        rowxl[tid] = (gr < R) ? rowx[gr] : -1;
    }
    // D layout: row = wm*128 + m*16 + g*4 + r ; col = wn*112 + n*16 + c
    #pragma unroll
    for (int m = 0; m < 8; ++m) {
        #pragma unroll
        for (int r = 0; r < 4; ++r) {
            float v = -FLT_MAX;
            #pragma unroll
            for (int n = 0; n < 7; ++n) {
                int nn = wn * 112 + n * 16 + c;
                if (nn < NI) v = fmaxf(v, acc[m][n][r]);
            }
            #pragma unroll
            for (int d = 1; d < 16; d <<= 1) v = fmaxf(v, __shfl_xor(v, d));
            if (c == 0) rowmax2[wn * 256 + wm * 128 + m * 16 + g * 4 + r] = v;
        }
    }
    __syncthreads();
    if (tid < 256) {
        int gr = m_base + tid;
        if (gr < R) {
            float rm = fmaxf(rowmax2[tid], rowmax2[256 + tid]);
            atomicAdd((float*)(ws + T2I_OFF) + rowxl[tid] * 64 + y, rm);
        }
    }
    int xr[8][4];
    #pragma unroll
    for (int m = 0; m < 8; ++m)
        #pragma unroll
        for (int r = 0; r < 4; ++r)
            xr[m][r] = rowxl[wm * 128 + m * 16 + g * 4 + r];

    unsigned* i2t = (unsigned*)(ws + I2T_OFF);
    #pragma unroll
    for (int n = 0; n < 7; ++n) {
        int nn = wn * 112 + n * 16 + c;
        if (nn >= NI) continue;
        int curx = -1; float curm = 0.f;
        #pragma unroll
        for (int m = 0; m < 8; ++m) {
            #pragma unroll
            for (int r = 0; r < 4; ++r) {
                int xv = xr[m][r];
                float v = acc[m][n][r];
                if (xv != curx) {
                    if (curx >= 0)
                        atomicMax(&i2t[(size_t)(curx * 64 + y) * NI + nn], mono_map(curm));
                    curx = xv; curm = v;
                } else {
                    curm = fmaxf(curm, v);
                }
            }
        }
        if (curx >= 0)
            atomicMax(&i2t[(size_t)(curx * 64 + y) * NI + nn], mono_map(curm));
    }
}

// fin: 64 blocks; each wave handles 16 (x,y) pairs; ONE atomicAdd per block.
__global__ __launch_bounds__(256) void fin_kernel(const int* __restrict__ tgt,
                                                  char* __restrict__ ws,
                                                  float* __restrict__ out) {
    const int wid = threadIdx.x >> 6, lane = threadIdx.x & 63;
    float bsum = 0.f;
    for (int rep = 0; rep < 16; ++rep) {
        int w = blockIdx.x * 64 + rep * 4 + wid;
        int x = w >> 6;
        const unsigned* iv = (const unsigned*)(ws + I2T_OFF) + (size_t)w * NI;
        float s = mono_unmap(iv[lane]) + mono_unmap(iv[64 + lane]) + mono_unmap(iv[128 + lane]);
        if (lane < 4) s += mono_unmap(iv[192 + lane]);
        #pragma unroll
        for (int d = 1; d < 64; d <<= 1) s += __shfl_xor(s, d);
        if (lane == 0) {
            float i2tv = s * (1.f / (float)NI);
            float t2is = ((const float*)(ws + T2I_OFF))[w];
            int   nvx  = ((const int*)(ws + NV_OFF))[x];
            float t2iv = t2is / fmaxf((float)nvx, EPS_);
            int tg = tgt[w];
            float mi  = (tg == 1) ? (1.f - i2tv) : fmaxf(i2tv - MARGIN_, 0.f);
            float mtv = (tg == 1) ? (1.f - t2iv) : fmaxf(t2iv - MARGIN_, 0.f);
            bsum += mi + mtv;
        }
    }
    __shared__ float p4[4];
    if (lane == 0) p4[wid] = bsum;
    __syncthreads();
    if (threadIdx.x == 0)
        atomicAdd(out, (p4[0] + p4[1] + p4[2] + p4[3]) * (1.f / 8192.f));
}

// ================= FALLBACK PATH (f32 VALU, known-correct) =================

__global__ __launch_bounds__(64) void prep0_kernel(const int* __restrict__ pm,
                                                   int* __restrict__ wsi,
                                                   float* __restrict__ out) {
    int x = threadIdx.x;
    if (x == 0) out[0] = 0.f;
    if (x >= B_) return;
    const int* row = pm + x * TTXT;
    int lastz = -1;
    for (int t = 0; t < TTXT; ++t) if (row[t] == 0) lastz = t;
    int eos = (lastz >= 0) ? lastz : 0;
    int nv = 0;
    int* vv = wsi + 64 + x * MT;
    for (int t = 1; t < TTXT; ++t) {
        int v = row[t];
        if (t == eos) v = 1;
        if (v == 0) vv[nv++] = t - 1;
    }
    wsi[x] = nv;
}

__global__ __launch_bounds__(256) void sim0_kernel(const float* __restrict__ img,
                                                   const float* __restrict__ txt,
                                                   const int* __restrict__ tgt,
                                                   const int* __restrict__ wsi,
                                                   float* __restrict__ out)
{
    const int bid = blockIdx.x;
    const int x = bid & 63;
    const int y = bid >> 6;
    const int tid = threadIdx.x;
    const int w = tid >> 6;
    const int c = tid & 63;

    __shared__ float sA[MT][DC];
    __shared__ float sB[NI][DC + 4];
    __shared__ float red[4 * 256];
    __shared__ float wred[8];

    const int nv = wsi[x];
    const int* vv = wsi + 64 + x * MT;

    const float* timg = img + (size_t)y * TIMG * DDIM + DDIM;
    const float* ttxt = txt + (size_t)x * TTXT * DDIM + DDIM;

    float acc[16][4];
    #pragma unroll
    for (int v = 0; v < 16; ++v)
        #pragma unroll
        for (int u = 0; u < 4; ++u) acc[v][u] = 0.f;

    for (int dc = 0; dc < DDIM; dc += DC) {
        __syncthreads();
        for (int r = tid; r < NI * 4; r += 256) {
            int row = r >> 2, seg = r & 3;
            float4 vsrc = *reinterpret_cast<const float4*>(
                timg + (size_t)row * DDIM + dc + seg * 4);
            *reinterpret_cast<float4*>(&sB[row][seg * 4]) = vsrc;
        }
        if (tid < nv * 4) {
            int j = tid >> 2, seg = tid & 3;
            int t = vv[j];
            float4 vsrc = *reinterpret_cast<const float4*>(
                ttxt + (size_t)t * DDIM + dc + seg * 4);
            *reinterpret_cast<float4*>(&sA[j][seg * 4]) = vsrc;
        }
        __syncthreads();
        #pragma unroll
        for (int ds = 0; ds < 4; ++ds) {
            float4 b0 = *reinterpret_cast<const float4*>(&sB[c][ds * 4]);
            float4 b1 = *reinterpret_cast<const float4*>(&sB[c + 64][ds * 4]);
            float4 b2 = *reinterpret_cast<const float4*>(&sB[c + 128][ds * 4]);
            float4 b3 = *reinterpret_cast<const float4*>(&sB[(c + 192 < NI) ? (c + 192) : (NI - 1)][ds * 4]);
            #pragma unroll
            for (int v = 0; v < 16; ++v) {
                int t = 4 * v + w;
                if (t < nv) {
                    float4 a = *reinterpret_cast<const float4*>(&sA[t][ds * 4]);
                    acc[v][0] += a.x * b0.x + a.y * b0.y + a.z * b0.z + a.w * b0.w;
                    acc[v][1] += a.x * b1.x + a.y * b1.y + a.z * b1.z + a.w * b1.w;
                    acc[v][2] += a.x * b2.x + a.y * b2.y + a.z * b2.z + a.w * b2.w;
                    acc[v][3] += a.x * b3.x + a.y * b3.y + a.z * b3.z + a.w * b3.w;
                }
            }
        }
    }

    float tsum = 0.f;
    float cmax[4] = {-FLT_MAX, -FLT_MAX, -FLT_MAX, -FLT_MAX};
    #pragma unroll
    for (int v = 0; v < 16; ++v) {
        int t = 4 * v + w;
        if (t < nv) {
            float r = -FLT_MAX;
            #pragma unroll
            for (int u = 0; u < 4; ++u) {
                int i = c + 64 * u;
                if (i < NI) {
                    float val = acc[v][u];
                    r = fmaxf(r, val);
                    cmax[u] = fmaxf(cmax[u], val);
                }
            }
            #pragma unroll
            for (int off = 1; off < 64; off <<= 1)
                r = fmaxf(r, __shfl_xor(r, off));
            tsum += r;
        }
    }

    __syncthreads();
    #pragma unroll
    for (int u = 0; u < 4; ++u)
        red[w * 256 + c + 64 * u] = cmax[u];
    if (c == 0) wred[w] = tsum;
    __syncthreads();

    float cm = 0.f;
    if (tid < NI) {
        float m0 = fmaxf(red[tid], red[256 + tid]);
        float m1 = fmaxf(red[512 + tid], red[768 + tid]);
        cm = fmaxf(m0, m1);
    }
    float s = cm;
    #pragma unroll
    for (int off = 1; off < 64; off <<= 1)
        s += __shfl_xor(s, off);
    if (c == 0) wred[4 + w] = s;
    __syncthreads();

    if (tid == 0) {
        float rowsum = wred[0] + wred[1] + wred[2] + wred[3];
        float colsum = wred[4] + wred[5] + wred[6] + wred[7];
        float t2i = rowsum / fmaxf((float)nv, EPS_);
        float i2t = colsum * (1.f / (float)NI);
        int tg = tgt[x * 64 + y];
        float mi = (tg == 1) ? (1.f - i2t) : fmaxf(i2t - MARGIN_, 0.f);
        float mt = (tg == 1) ? (1.f - t2i) : fmaxf(t2i - MARGIN_, 0.f);
        atomicAdd(out, (mi + mt) * (1.f / 8192.f));
    }
}

// ================= launcher =================

extern "C" void kernel_launch(void* const* d_in, const int* in_sizes, int n_in,
                              void* d_out, int out_size, void* d_ws, size_t ws_size,
                              hipStream_t stream) {
    const float* img = (const float*)d_in[0];
    const float* txt = (const float*)d_in[1];
    const int*   pm  = (const int*)d_in[2];
    const int*   tgt = (const int*)d_in[3];
    float* out = (float*)d_out;

    if (ws_size >= (size_t)WS_NEEDED) {
        char* wsc = (char*)d_ws;
        hipLaunchKernelGGL(prep_kernel, dim3(1),    dim3(64),  0, stream, pm, wsc, out);
        hipLaunchKernelGGL(conv_kernel, dim3(7697), dim3(256), 0, stream, img, txt, wsc);
        hipLaunchKernelGGL(gemm_kernel, dim3(1024), dim3(256), 0, stream, wsc);
        hipLaunchKernelGGL(fin_kernel,  dim3(64),   dim3(256), 0, stream, tgt, wsc, out);
    } else {
        int* wsi = (int*)d_ws;
        hipLaunchKernelGGL(prep0_kernel, dim3(1),    dim3(64),  0, stream, pm, wsi, out);
        hipLaunchKernelGGL(sim0_kernel,  dim3(4096), dim3(256), 0, stream,
                           img, txt, tgt, wsi, out);
    }
}

// Round 8
// 287.843 us; speedup vs baseline: 1.3278x; 1.3278x over previous
//
#include <hip/hip_runtime.h>
#include <float.h>
#include <stdint.h>

#define B_      64
#define TTXT    64
#define TIMG    197
#define DDIM    768
#define MT      63
#define NI      196
#define NPAD    224
#define DC      16
#define MARGIN_ 0.5f
#define EPS_    1e-6f

// ---- ws byte offsets ----
#define META_OFF   0u          // int meta[16]; meta[0] = R
#define NV_OFF     64u         // int nv[64]
#define ROWSRC_OFF 320u        // int rowsrc[4096]
#define ROWX_OFF   16704u      // int rowx[4096]
#define T2I_OFF    33088u      // float t2i_sum[4096]
#define I2T_OFF    49472u      // uint i2t_part[64*64*196]
// A image: [4096 rows][24 chunks][hi: 4 slots][lo: 4 slots] (3072 B/row), NO xor
#define AIMG_OFF   3260736u
// B image: [64*224 rows][24 chunks][hi 4][lo 4]
#define BIMG_OFF   15843648u
#define WS_NEEDED  59883840u

typedef _Float16 f16x8 __attribute__((ext_vector_type(8)));
typedef float    f32x4 __attribute__((ext_vector_type(4)));

__device__ __forceinline__ unsigned mono_map(float v) {
    unsigned b = __float_as_uint(v);
    return (b & 0x80000000u) ? ~b : (b | 0x80000000u);
}
__device__ __forceinline__ float mono_unmap(unsigned u) {
    unsigned b = (u & 0x80000000u) ? (u & 0x7fffffffu) : ~u;
    return __uint_as_float(b);
}

__device__ __forceinline__ void async_ld16(const void* g, void* l) {
    __builtin_amdgcn_global_load_lds((const __attribute__((address_space(1))) void*)g,
                                     (__attribute__((address_space(3))) void*)l,
                                     16, 0, 0);
}

#define VMW(n) asm volatile("s_waitcnt vmcnt(" #n ")" ::: "memory")

// ================= FAST PATH =================

__global__ __launch_bounds__(64) void prep_kernel(const int* __restrict__ pm,
                                                  char* __restrict__ ws,
                                                  float* __restrict__ out) {
    int x = threadIdx.x;
    if (x == 0) out[0] = 0.f;                 // fin accumulates via atomics
    int* meta   = (int*)(ws + META_OFF);
    int* nv     = (int*)(ws + NV_OFF);
    int* rowsrc = (int*)(ws + ROWSRC_OFF);
    int* rowx   = (int*)(ws + ROWX_OFF);
    const int* row = pm + x * TTXT;
    int lastz = -1;
    for (int t = 0; t < TTXT; ++t) if (row[t] == 0) lastz = t;
    int eos = (lastz >= 0) ? lastz : 0;
    int cnt = 0; int loc[63];
    for (int t = 1; t < TTXT; ++t) {
        int v = row[t]; if (t == eos) v = 1;
        if (v == 0) loc[cnt++] = t;
    }
    int s = cnt;
    for (int d = 1; d < 64; d <<= 1) { int o = __shfl_up(s, d); if (x >= d) s += o; }
    int off = s - cnt;
    for (int j = 0; j < cnt; ++j) {
        rowsrc[off + j] = (x * TTXT + loc[j]) * DDIM;
        rowx[off + j] = x;
    }
    nv[x] = cnt;
    if (x == 63) meta[0] = off + cnt;    // R
}

// conv: plain hi/lo chunk images (no XOR — swizzle moved to gemm's per-lane
// DMA source gather) + init of reduction buffers. thread = (row, kc, group)
// reads 32B once, emits hi slot g and lo slot 4+g. grid 7697.
__global__ __launch_bounds__(256) void conv_kernel(const float* __restrict__ img,
                                                   const float* __restrict__ txt,
                                                   char* __restrict__ ws) {
    const int bid = blockIdx.x, tid = threadIdx.x;
    if (bid < 1536) {                              // ---- A: 4096 rows x 24 kc x 4 groups
        int gid = bid * 256 + tid;
        int g  = gid & 3;
        int kc = (gid >> 2) % 24;
        int gr = gid / 96;
        const int R = *(const int*)(ws + META_OFF);
        f16x8 hv = 0, lv = 0;
        if (gr < R) {
            const int* rowsrc = (const int*)(ws + ROWSRC_OFF);
            const float* src = txt + rowsrc[gr] + kc * 32 + g * 8;
            float4 f0 = ((const float4*)src)[0];
            float4 f1 = ((const float4*)src)[1];
            float fv[8] = {f0.x, f0.y, f0.z, f0.w, f1.x, f1.y, f1.z, f1.w};
            #pragma unroll
            for (int j = 0; j < 8; ++j) {
                float fx = fv[j];
                _Float16 hh = (_Float16)fx;
                hv[j] = hh;
                lv[j] = (_Float16)(fx - (float)hh);
            }
        }
        char* base = ws + AIMG_OFF + (size_t)gr * 3072 + kc * 128;
        *(f16x8*)(base + g * 16)      = hv;
        *(f16x8*)(base + 64 + g * 16) = lv;
    } else if (bid < 6912) {                       // ---- B: 14336 rows x 24 kc x 4 groups
        int gid = (bid - 1536) * 256 + tid;
        int g  = gid & 3;
        int kc = (gid >> 2) % 24;
        int rr = gid / 96;
        int y = rr / NPAD, i = rr % NPAD;
        f16x8 hv = 0, lv = 0;
        if (i < NI) {
            const float* src = img + (size_t)(y * TIMG + i + 1) * DDIM + kc * 32 + g * 8;
            float4 f0 = ((const float4*)src)[0];
            float4 f1 = ((const float4*)src)[1];
            float fv[8] = {f0.x, f0.y, f0.z, f0.w, f1.x, f1.y, f1.z, f1.w};
            #pragma unroll
            for (int j = 0; j < 8; ++j) {
                float fx = fv[j];
                _Float16 hh = (_Float16)fx;
                hv[j] = hh;
                lv[j] = (_Float16)(fx - (float)hh);
            }
        }
        char* base = ws + BIMG_OFF + (size_t)rr * 3072 + kc * 128;
        *(f16x8*)(base + g * 16)      = hv;
        *(f16x8*)(base + 64 + g * 16) = lv;
    } else if (bid < 7696) {                       // ---- i2t init (200704 uint4)
        int gid = (bid - 6912) * 256 + tid;
        uint4 v = make_uint4(0x00800000u, 0x00800000u, 0x00800000u, 0x00800000u);
        ((uint4*)(ws + I2T_OFF))[gid] = v;         // mono(-FLT_MAX)
    } else {                                       // ---- t2i init (1024 uint4)
        uint4 z = make_uint4(0u, 0u, 0u, 0u);
        #pragma unroll
        for (int j = 0; j < 4; ++j)
            ((uint4*)(ws + T2I_OFF))[tid * 4 + j] = z;
    }
}

// gemm: grid 1024 = 16 m-tiles(256) x 64 y; 512 thr (8 waves, 4wm x 2wn,
// wave tile 64x112, acc[4][7]). 3-phase chunk schedule, counted vmcnt (T3+T4)
// + setprio (T5). LDS buffer regions (61440 B each, x2):
//   A_hi [0,16384) | A_lo [16384,32768) | B_hi [32768,47104) | B_lo [47104,61440)
// Each region: row*64 + j'*16, j' = j ^ ((row>>1)&3) (2-bit swizzle; within any
// 16 lanes a b128 read hits 8 distinct positions/128B -> 2-way = free, m136).
// DMA dst is LINEAR region + p*16 (rule #21: uniform + lane*16); the swizzle
// lives in the per-lane global SOURCE address (m173).
//   ph1(hh): read ah,bh(Hi_k) | issue Lo_{k+1} | MFMA | VMW(8/6) pub Lo_k | bar
//   ph2(hl): read bl(Lo_k)    | issue Hi_{k+2} | MFMA
//   ph3(lh): read al(Lo_k)    |                | MFMA | VMW(8/6) pub Hi_{k+1} | bar
__global__ __launch_bounds__(512, 1) void gemm_kernel(char* __restrict__ ws) {
    const int bid = blockIdx.x;
    const int swz = (bid & 7) * 128 + (bid >> 3);   // XCD-chunked, bijective
    const int mt  = swz & 15;
    const int y   = swz >> 4;
    const int R = *(const int*)(ws + META_OFF);
    const int m_base = mt * 256;
    if (m_base >= R) return;

    const int tid = threadIdx.x;
    const int wid = tid >> 6, lane = tid & 63;
    const int c = lane & 15, g = lane >> 4;
    const int wm = wid >> 1, wn = wid & 1;
    const bool hiw = (wid < 6);      // waves 0-5 stage 4 loads/half, 6-7 stage 3

    __shared__ __align__(16) unsigned char lds[122880];  // 2 x 61440

    f32x4 acc[4][7];
    #pragma unroll
    for (int m = 0; m < 4; ++m)
        #pragma unroll
        for (int n = 0; n < 7; ++n) acc[m][n] = 0.f;

    const char* Abp = ws + AIMG_OFF + (size_t)m_base * 3072;
    const char* Bbp = ws + BIMG_OFF + (size_t)(y * NPAD) * 3072;

    // per-lane source offsets (excl. kc/lo): LDS position p holds image
    // row = p>>2, k-slot j = (p&3) ^ ((row>>1)&3)
    int a_srcoff[2];
    #pragma unroll
    for (int rep = 0; rep < 2; ++rep) {
        int p = tid + rep * 512, row = p >> 2, j = (p & 3) ^ ((row >> 1) & 3);
        a_srcoff[rep] = row * 3072 + j * 16;
    }
    int b_srcoff[2] = {0, 0};
    { int p = tid, row = p >> 2, j = (p & 3) ^ ((row >> 1) & 3);
      b_srcoff[0] = row * 3072 + j * 16; }
    if (tid < 384) {
      int p = 512 + tid, row = p >> 2, j = (p & 3) ^ ((row >> 1) & 3);
      b_srcoff[1] = row * 3072 + j * 16; }

    auto STAGE = [&](unsigned char* base, int kc, int lo) {
        const int ko = kc * 128 + (lo << 6);       // hi at +0, lo at +64 in image
        unsigned char* ab = base + (lo ? 16384 : 0);
        unsigned char* bb = base + (lo ? 47104 : 32768);
        async_ld16(Abp + a_srcoff[0] + ko, ab + tid * 16);
        async_ld16(Abp + a_srcoff[1] + ko, ab + 8192 + tid * 16);
        async_ld16(Bbp + b_srcoff[0] + ko, bb + tid * 16);
        if (tid < 384)
            async_ld16(Bbp + b_srcoff[1] + ko, bb + 8192 + tid * 16);
    };

    // fragment read offsets (swizzled)
    int aofh[4], aofl[4], bofh[7], bofl[7];
    #pragma unroll
    for (int m = 0; m < 4; ++m) {
        int r = wm * 64 + m * 16 + c, sw = (r >> 1) & 3;
        aofh[m] = r * 64 + ((g ^ sw) << 4);
        aofl[m] = aofh[m] + 16384;
    }
    #pragma unroll
    for (int n = 0; n < 7; ++n) {
        int i = wn * 112 + n * 16 + c, sw = (i >> 1) & 3;
        bofh[n] = 32768 + i * 64 + ((g ^ sw) << 4);
        bofl[n] = bofh[n] + 14336;
    }

    // prologue: Hi_0, Lo_0 -> buf0; Hi_1 -> buf1; publish Hi_0
    STAGE(lds, 0, 0);
    STAGE(lds, 0, 1);
    STAGE(lds + 61440, 1, 0);
    if (hiw) VMW(8); else VMW(6);
    __builtin_amdgcn_s_barrier();

    f16x8 ah[4], bh[7];

    #pragma unroll 2
    for (int kc = 0; kc < 22; ++kc) {
        unsigned char* cb = lds + (kc & 1) * 61440;
        unsigned char* nb = lds + ((kc + 1) & 1) * 61440;
        // ---- ph1: hh ----
        #pragma unroll
        for (int m = 0; m < 4; ++m) ah[m] = *(const f16x8*)(cb + aofh[m]);
        #pragma unroll
        for (int n = 0; n < 7; ++n) bh[n] = *(const f16x8*)(cb + bofh[n]);
        STAGE(nb, kc + 1, 1);                       // Lo_{k+1}
        __builtin_amdgcn_s_setprio(1);
        #pragma unroll
        for (int m = 0; m < 4; ++m)
            #pragma unroll
            for (int n = 0; n < 7; ++n)
                acc[m][n] = __builtin_amdgcn_mfma_f32_16x16x32_f16(ah[m], bh[n], acc[m][n], 0, 0, 0);
        __builtin_amdgcn_s_setprio(0);
        if (hiw) VMW(8); else VMW(6);               // publish Lo_k
        __builtin_amdgcn_s_barrier();
        // ---- ph2: hl ----
        {
            f16x8 bl[7];
            #pragma unroll
            for (int n = 0; n < 7; ++n) bl[n] = *(const f16x8*)(cb + bofl[n]);
            STAGE(cb, kc + 2, 0);                   // Hi_{k+2} (Hi_k readers done @B1)
            __builtin_amdgcn_s_setprio(1);
            #pragma unroll
            for (int m = 0; m < 4; ++m)
                #pragma unroll
                for (int n = 0; n < 7; ++n)
                    acc[m][n] = __builtin_amdgcn_mfma_f32_16x16x32_f16(ah[m], bl[n], acc[m][n], 0, 0, 0);
            __builtin_amdgcn_s_setprio(0);
        }
        // ---- ph3: lh ----
        {
            f16x8 al[4];
            #pragma unroll
            for (int m = 0; m < 4; ++m) al[m] = *(const f16x8*)(cb + aofl[m]);
            __builtin_amdgcn_s_setprio(1);
            #pragma unroll
            for (int m = 0; m < 4; ++m)
                #pragma unroll
                for (int n = 0; n < 7; ++n)
                    acc[m][n] = __builtin_amdgcn_mfma_f32_16x16x32_f16(al[m], bh[n], acc[m][n], 0, 0, 0);
            __builtin_amdgcn_s_setprio(0);
        }
        if (hiw) VMW(8); else VMW(6);               // publish Hi_{k+1}
        __builtin_amdgcn_s_barrier();
    }
    // ---- peeled kc=22 (no Hi_24 issue; tail wait 4/3) ----
    {
        unsigned char* cb = lds;            // 22&1 = 0
        unsigned char* nb = lds + 61440;
        #pragma unroll
        for (int m = 0; m < 4; ++m) ah[m] = *(const f16x8*)(cb + aofh[m]);
        #pragma unroll
        for (int n = 0; n < 7; ++n) bh[n] = *(const f16x8*)(cb + bofh[n]);
        STAGE(nb, 23, 1);                           // Lo_23
        __builtin_amdgcn_s_setprio(1);
        #pragma unroll
        for (int m = 0; m < 4; ++m)
            #pragma unroll
            for (int n = 0; n < 7; ++n)
                acc[m][n] = __builtin_amdgcn_mfma_f32_16x16x32_f16(ah[m], bh[n], acc[m][n], 0, 0, 0);
        __builtin_amdgcn_s_setprio(0);
        if (hiw) VMW(8); else VMW(6);               // publish Lo_22
        __builtin_amdgcn_s_barrier();
        {
            f16x8 bl[7];
            #pragma unroll
            for (int n = 0; n < 7; ++n) bl[n] = *(const f16x8*)(cb + bofl[n]);
            __builtin_amdgcn_s_setprio(1);
            #pragma unroll
            for (int m = 0; m < 4; ++m)
                #pragma unroll
                for (int n = 0; n < 7; ++n)
                    acc[m][n] = __builtin_amdgcn_mfma_f32_16x16x32_f16(ah[m], bl[n], acc[m][n], 0, 0, 0);
            __builtin_amdgcn_s_setprio(0);
        }
        {
            f16x8 al[4];
            #pragma unroll
            for (int m = 0; m < 4; ++m) al[m] = *(const f16x8*)(cb + aofl[m]);
            __builtin_amdgcn_s_setprio(1);
            #pragma unroll
            for (int m = 0; m < 4; ++m)
                #pragma unroll
                for (int n = 0; n < 7; ++n)
                    acc[m][n] = __builtin_amdgcn_mfma_f32_16x16x32_f16(al[m], bh[n], acc[m][n], 0, 0, 0);
            __builtin_amdgcn_s_setprio(0);
        }
        if (hiw) VMW(4); else VMW(3);               // publish Hi_23 (only Lo_23 newer)
        __builtin_amdgcn_s_barrier();
    }
    // ---- peeled kc=23 (no staging; final drain once) ----
    {
        unsigned char* cb = lds + 61440;
        #pragma unroll
        for (int m = 0; m < 4; ++m) ah[m] = *(const f16x8*)(cb + aofh[m]);
        #pragma unroll
        for (int n = 0; n < 7; ++n) bh[n] = *(const f16x8*)(cb + bofh[n]);
        __builtin_amdgcn_s_setprio(1);
        #pragma unroll
        for (int m = 0; m < 4; ++m)
            #pragma unroll
            for (int n = 0; n < 7; ++n)
                acc[m][n] = __builtin_amdgcn_mfma_f32_16x16x32_f16(ah[m], bh[n], acc[m][n], 0, 0, 0);
        __builtin_amdgcn_s_setprio(0);
        VMW(0);                                     // publish Lo_23 (nothing newer)
        __builtin_amdgcn_s_barrier();
        {
            f16x8 bl[7];
            #pragma unroll
            for (int n = 0; n < 7; ++n) bl[n] = *(const f16x8*)(cb + bofl[n]);
            __builtin_amdgcn_s_setprio(1);
            #pragma unroll
            for (int m = 0; m < 4; ++m)
                #pragma unroll
                for (int n = 0; n < 7; ++n)
                    acc[m][n] = __builtin_amdgcn_mfma_f32_16x16x32_f16(ah[m], bl[n], acc[m][n], 0, 0, 0);
            __builtin_amdgcn_s_setprio(0);
        }
        {
            f16x8 al[4];
            #pragma unroll
            for (int m = 0; m < 4; ++m) al[m] = *(const f16x8*)(cb + aofl[m]);
            __builtin_amdgcn_s_setprio(1);
            #pragma unroll
            for (int m = 0; m < 4; ++m)
                #pragma unroll
                for (int n = 0; n < 7; ++n)
                    acc[m][n] = __builtin_amdgcn_mfma_f32_16x16x32_f16(al[m], bh[n], acc[m][n], 0, 0, 0);
            __builtin_amdgcn_s_setprio(0);
        }
    }
    __syncthreads();                                // full drain; lds reused below

    // ---- epilogue (r4/r5 verified) ----
    float* rowmax2 = (float*)lds;            // [2][256]
    int*   rowxl   = (int*)(lds + 2048);     // [256]
    const int* rowx = (const int*)(ws + ROWX_OFF);
    if (tid < 256) {
        int gr = m_base + tid;
        rowxl[tid] = (gr < R) ? rowx[gr] : -1;
    }
    // D layout: row = wm*64 + m*16 + g*4 + r ; col = wn*112 + n*16 + c
    #pragma unroll
    for (int m = 0; m < 4; ++m) {
        #pragma unroll
        for (int r = 0; r < 4; ++r) {
            float v = -FLT_MAX;
            #pragma unroll
            for (int n = 0; n < 7; ++n) {
                int nn = wn * 112 + n * 16 + c;
                if (nn < NI) v = fmaxf(v, acc[m][n][r]);
            }
            #pragma unroll
            for (int d = 1; d < 16; d <<= 1) v = fmaxf(v, __shfl_xor(v, d));
            if (c == 0) rowmax2[wn * 256 + wm * 64 + m * 16 + g * 4 + r] = v;
        }
    }
    __syncthreads();
    if (tid < 256) {
        int gr = m_base + tid;
        if (gr < R) {
            float rm = fmaxf(rowmax2[tid], rowmax2[256 + tid]);
            atomicAdd((float*)(ws + T2I_OFF) + rowxl[tid] * 64 + y, rm);
        }
    }
    int xr[4][4];
    #pragma unroll
    for (int m = 0; m < 4; ++m)
        #pragma unroll
        for (int r = 0; r < 4; ++r)
            xr[m][r] = rowxl[wm * 64 + m * 16 + g * 4 + r];

    unsigned* i2t = (unsigned*)(ws + I2T_OFF);
    #pragma unroll
    for (int n = 0; n < 7; ++n) {
        int nn = wn * 112 + n * 16 + c;
        if (nn >= NI) continue;
        int curx = -1; float curm = 0.f;
        #pragma unroll
        for (int m = 0; m < 4; ++m) {
            #pragma unroll
            for (int r = 0; r < 4; ++r) {
                int xv = xr[m][r];
                float v = acc[m][n][r];
                if (xv != curx) {
                    if (curx >= 0)
                        atomicMax(&i2t[(size_t)(curx * 64 + y) * NI + nn], mono_map(curm));
                    curx = xv; curm = v;
                } else {
                    curm = fmaxf(curm, v);
                }
            }
        }
        if (curx >= 0)
            atomicMax(&i2t[(size_t)(curx * 64 + y) * NI + nn], mono_map(curm));
    }
}

// fin: 64 blocks; each wave handles 16 (x,y) pairs; ONE atomicAdd per block.
__global__ __launch_bounds__(256) void fin_kernel(const int* __restrict__ tgt,
                                                  char* __restrict__ ws,
                                                  float* __restrict__ out) {
    const int wid = threadIdx.x >> 6, lane = threadIdx.x & 63;
    float bsum = 0.f;
    for (int rep = 0; rep < 16; ++rep) {
        int w = blockIdx.x * 64 + rep * 4 + wid;
        int x = w >> 6;
        const unsigned* iv = (const unsigned*)(ws + I2T_OFF) + (size_t)w * NI;
        float s = mono_unmap(iv[lane]) + mono_unmap(iv[64 + lane]) + mono_unmap(iv[128 + lane]);
        if (lane < 4) s += mono_unmap(iv[192 + lane]);
        #pragma unroll
        for (int d = 1; d < 64; d <<= 1) s += __shfl_xor(s, d);
        if (lane == 0) {
            float i2tv = s * (1.f / (float)NI);
            float t2is = ((const float*)(ws + T2I_OFF))[w];
            int   nvx  = ((const int*)(ws + NV_OFF))[x];
            float t2iv = t2is / fmaxf((float)nvx, EPS_);
            int tg = tgt[w];
            float mi  = (tg == 1) ? (1.f - i2tv) : fmaxf(i2tv - MARGIN_, 0.f);
            float mtv = (tg == 1) ? (1.f - t2iv) : fmaxf(t2iv - MARGIN_, 0.f);
            bsum += mi + mtv;
        }
    }
    __shared__ float p4[4];
    if (lane == 0) p4[wid] = bsum;
    __syncthreads();
    if (threadIdx.x == 0)
        atomicAdd(out, (p4[0] + p4[1] + p4[2] + p4[3]) * (1.f / 8192.f));
}

// ================= FALLBACK PATH (f32 VALU, known-correct) =================

__global__ __launch_bounds__(64) void prep0_kernel(const int* __restrict__ pm,
                                                   int* __restrict__ wsi,
                                                   float* __restrict__ out) {
    int x = threadIdx.x;
    if (x == 0) out[0] = 0.f;
    if (x >= B_) return;
    const int* row = pm + x * TTXT;
    int lastz = -1;
    for (int t = 0; t < TTXT; ++t) if (row[t] == 0) lastz = t;
    int eos = (lastz >= 0) ? lastz : 0;
    int nv = 0;
    int* vv = wsi + 64 + x * MT;
    for (int t = 1; t < TTXT; ++t) {
        int v = row[t];
        if (t == eos) v = 1;
        if (v == 0) vv[nv++] = t - 1;
    }
    wsi[x] = nv;
}

__global__ __launch_bounds__(256) void sim0_kernel(const float* __restrict__ img,
                                                   const float* __restrict__ txt,
                                                   const int* __restrict__ tgt,
                                                   const int* __restrict__ wsi,
                                                   float* __restrict__ out)
{
    const int bid = blockIdx.x;
    const int x = bid & 63;
    const int y = bid >> 6;
    const int tid = threadIdx.x;
    const int w = tid >> 6;
    const int c = tid & 63;

    __shared__ float sA[MT][DC];
    __shared__ float sB[NI][DC + 4];
    __shared__ float red[4 * 256];
    __shared__ float wred[8];

    const int nv = wsi[x];
    const int* vv = wsi + 64 + x * MT;

    const float* timg = img + (size_t)y * TIMG * DDIM + DDIM;
    const float* ttxt = txt + (size_t)x * TTXT * DDIM + DDIM;

    float acc[16][4];
    #pragma unroll
    for (int v = 0; v < 16; ++v)
        #pragma unroll
        for (int u = 0; u < 4; ++u) acc[v][u] = 0.f;

    for (int dc = 0; dc < DDIM; dc += DC) {
        __syncthreads();
        for (int r = tid; r < NI * 4; r += 256) {
            int row = r >> 2, seg = r & 3;
            float4 vsrc = *reinterpret_cast<const float4*>(
                timg + (size_t)row * DDIM + dc + seg * 4);
            *reinterpret_cast<float4*>(&sB[row][seg * 4]) = vsrc;
        }
        if (tid < nv * 4) {
            int j = tid >> 2, seg = tid & 3;
            int t = vv[j];
            float4 vsrc = *reinterpret_cast<const float4*>(
                ttxt + (size_t)t * DDIM + dc + seg * 4);
            *reinterpret_cast<float4*>(&sA[j][seg * 4]) = vsrc;
        }
        __syncthreads();
        #pragma unroll
        for (int ds = 0; ds < 4; ++ds) {
            float4 b0 = *reinterpret_cast<const float4*>(&sB[c][ds * 4]);
            float4 b1 = *reinterpret_cast<const float4*>(&sB[c + 64][ds * 4]);
            float4 b2 = *reinterpret_cast<const float4*>(&sB[c + 128][ds * 4]);
            float4 b3 = *reinterpret_cast<const float4*>(&sB[(c + 192 < NI) ? (c + 192) : (NI - 1)][ds * 4]);
            #pragma unroll
            for (int v = 0; v < 16; ++v) {
                int t = 4 * v + w;
                if (t < nv) {
                    float4 a = *reinterpret_cast<const float4*>(&sA[t][ds * 4]);
                    acc[v][0] += a.x * b0.x + a.y * b0.y + a.z * b0.z + a.w * b0.w;
                    acc[v][1] += a.x * b1.x + a.y * b1.y + a.z * b1.z + a.w * b1.w;
                    acc[v][2] += a.x * b2.x + a.y * b2.y + a.z * b2.z + a.w * b2.w;
                    acc[v][3] += a.x * b3.x + a.y * b3.y + a.z * b3.z + a.w * b3.w;
                }
            }
        }
    }

    float tsum = 0.f;
    float cmax[4] = {-FLT_MAX, -FLT_MAX, -FLT_MAX, -FLT_MAX};
    #pragma unroll
    for (int v = 0; v < 16; ++v) {
        int t = 4 * v + w;
        if (t < nv) {
            float r = -FLT_MAX;
            #pragma unroll
            for (int u = 0; u < 4; ++u) {
                int i = c + 64 * u;
                if (i < NI) {
                    float val = acc[v][u];
                    r = fmaxf(r, val);
                    cmax[u] = fmaxf(cmax[u], val);
                }
            }
            #pragma unroll
            for (int off = 1; off < 64; off <<= 1)
                r = fmaxf(r, __shfl_xor(r, off));
            tsum += r;
        }
    }

    __syncthreads();
    #pragma unroll
    for (int u = 0; u < 4; ++u)
        red[w * 256 + c + 64 * u] = cmax[u];
    if (c == 0) wred[w] = tsum;
    __syncthreads();

    float cm = 0.f;
    if (tid < NI) {
        float m0 = fmaxf(red[tid], red[256 + tid]);
        float m1 = fmaxf(red[512 + tid], red[768 + tid]);
        cm = fmaxf(m0, m1);
    }
    float s = cm;
    #pragma unroll
    for (int off = 1; off < 64; off <<= 1)
        s += __shfl_xor(s, off);
    if (c == 0) wred[4 + w] = s;
    __syncthreads();

    if (tid == 0) {
        float rowsum = wred[0] + wred[1] + wred[2] + wred[3];
        float colsum = wred[4] + wred[5] + wred[6] + wred[7];
        float t2i = rowsum / fmaxf((float)nv, EPS_);
        float i2t = colsum * (1.f / (float)NI);
        int tg = tgt[x * 64 + y];
        float mi = (tg == 1) ? (1.f - i2t) : fmaxf(i2t - MARGIN_, 0.f);
        float mt = (tg == 1) ? (1.f - t2i) : fmaxf(t2i - MARGIN_, 0.f);
        atomicAdd(out, (mi + mt) * (1.f / 8192.f));
    }
}

// ================= launcher =================

extern "C" void kernel_launch(void* const* d_in, const int* in_sizes, int n_in,
                              void* d_out, int out_size, void* d_ws, size_t ws_size,
                              hipStream_t stream) {
    const float* img = (const float*)d_in[0];
    const float* txt = (const float*)d_in[1];
    const int*   pm  = (const int*)d_in[2];
    const int*   tgt = (const int*)d_in[3];
    float* out = (float*)d_out;

    if (ws_size >= (size_t)WS_NEEDED) {
        char* wsc = (char*)d_ws;
        hipLaunchKernelGGL(prep_kernel, dim3(1),    dim3(64),  0, stream, pm, wsc, out);
        hipLaunchKernelGGL(conv_kernel, dim3(7697), dim3(256), 0, stream, img, txt, wsc);
        hipLaunchKernelGGL(gemm_kernel, dim3(1024), dim3(512), 0, stream, wsc);
        hipLaunchKernelGGL(fin_kernel,  dim3(64),   dim3(256), 0, stream, tgt, wsc, out);
    } else {
        int* wsi = (int*)d_ws;
        hipLaunchKernelGGL(prep0_kernel, dim3(1),    dim3(64),  0, stream, pm, wsi, out);
        hipLaunchKernelGGL(sim0_kernel,  dim3(4096), dim3(256), 0, stream,
                           img, txt, tgt, wsi, out);
    }
}

// Round 9
// 217.806 us; speedup vs baseline: 1.7548x; 1.3216x over previous
//
#include <hip/hip_runtime.h>
#include <float.h>
#include <stdint.h>

#define B_      64
#define TTXT    64
#define TIMG    197
#define DDIM    768
#define MT      63
#define NI      196
#define NPAD    224
#define DC      16
#define MARGIN_ 0.5f
#define EPS_    1e-6f

// ---- ws byte offsets ----
#define META_OFF   0u          // int meta[16]; meta[0] = R
#define NV_OFF     64u         // int nv[64]
#define ROWSRC_OFF 320u        // int rowsrc[4096]
#define ROWX_OFF   16704u      // int rowx[4096]
#define T2I_OFF    33088u      // float t2i_sum[4096]
#define I2T_OFF    49472u      // uint i2t_part[64*64*196]
// A image: [4096 rows][24 kc][4 slots][16B] single f16 plane (1536 B/row)
#define AIMG_OFF   3260736u
// B image: [64*224 rows][24 kc][4 slots][16B] (1536 B/row)
#define BIMG_OFF   9552192u
#define WS_NEEDED  59883840u

typedef _Float16 f16x8 __attribute__((ext_vector_type(8)));
typedef float    f32x4 __attribute__((ext_vector_type(4)));

__device__ __forceinline__ unsigned mono_map(float v) {
    unsigned b = __float_as_uint(v);
    return (b & 0x80000000u) ? ~b : (b | 0x80000000u);
}
__device__ __forceinline__ float mono_unmap(unsigned u) {
    unsigned b = (u & 0x80000000u) ? (u & 0x7fffffffu) : ~u;
    return __uint_as_float(b);
}

__device__ __forceinline__ void async_ld16(const void* g, void* l) {
    __builtin_amdgcn_global_load_lds((const __attribute__((address_space(1))) void*)g,
                                     (__attribute__((address_space(3))) void*)l,
                                     16, 0, 0);
}

// ================= FAST PATH =================

__global__ __launch_bounds__(64) void prep_kernel(const int* __restrict__ pm,
                                                  char* __restrict__ ws,
                                                  float* __restrict__ out) {
    int x = threadIdx.x;
    if (x == 0) out[0] = 0.f;                 // fin accumulates via atomics
    int* meta   = (int*)(ws + META_OFF);
    int* nv     = (int*)(ws + NV_OFF);
    int* rowsrc = (int*)(ws + ROWSRC_OFF);
    int* rowx   = (int*)(ws + ROWX_OFF);
    const int* row = pm + x * TTXT;
    int lastz = -1;
    for (int t = 0; t < TTXT; ++t) if (row[t] == 0) lastz = t;
    int eos = (lastz >= 0) ? lastz : 0;
    int cnt = 0; int loc[63];
    for (int t = 1; t < TTXT; ++t) {
        int v = row[t]; if (t == eos) v = 1;
        if (v == 0) loc[cnt++] = t;
    }
    int s = cnt;
    for (int d = 1; d < 64; d <<= 1) { int o = __shfl_up(s, d); if (x >= d) s += o; }
    int off = s - cnt;
    for (int j = 0; j < cnt; ++j) {
        rowsrc[off + j] = (x * TTXT + loc[j]) * DDIM;
        rowx[off + j] = x;
    }
    nv[x] = cnt;
    if (x == 63) meta[0] = off + cnt;    // R
}

// conv: single f16 plane images (threshold 1.275 makes the hi/lo split
// unnecessary) + init of reduction buffers. thread = one 16B slot: reads 32B
// f32, writes 16B f16. Plain slot order; swizzle lives in gemm's per-lane
// DMA source gather (r8-verified). grid 7697:
// [0,1536) A, [1536,6912) B, [6912,7696) i2t init, 7696 t2i init
__global__ __launch_bounds__(256) void conv_kernel(const float* __restrict__ img,
                                                   const float* __restrict__ txt,
                                                   char* __restrict__ ws) {
    const int bid = blockIdx.x, tid = threadIdx.x;
    if (bid < 1536) {                              // ---- A: 4096 rows x 24 kc x 4 slots
        int gid = bid * 256 + tid;
        int s  = gid & 3;
        int kc = (gid >> 2) % 24;
        int gr = gid / 96;
        const int R = *(const int*)(ws + META_OFF);
        f16x8 v = 0;
        if (gr < R) {
            const int* rowsrc = (const int*)(ws + ROWSRC_OFF);
            const float* src = txt + rowsrc[gr] + kc * 32 + s * 8;
            float4 f0 = ((const float4*)src)[0];
            float4 f1 = ((const float4*)src)[1];
            float fv[8] = {f0.x, f0.y, f0.z, f0.w, f1.x, f1.y, f1.z, f1.w};
            #pragma unroll
            for (int j = 0; j < 8; ++j) v[j] = (_Float16)fv[j];
        }
        *(f16x8*)(ws + AIMG_OFF + (size_t)gid * 16) = v;   // gr*1536 + kc*64 + s*16
    } else if (bid < 6912) {                       // ---- B: 14336 rows x 24 kc x 4 slots
        int gid = (bid - 1536) * 256 + tid;
        int s  = gid & 3;
        int kc = (gid >> 2) % 24;
        int rr = gid / 96;
        int y = rr / NPAD, i = rr % NPAD;
        f16x8 v = 0;
        if (i < NI) {
            const float* src = img + (size_t)(y * TIMG + i + 1) * DDIM + kc * 32 + s * 8;
            float4 f0 = ((const float4*)src)[0];
            float4 f1 = ((const float4*)src)[1];
            float fv[8] = {f0.x, f0.y, f0.z, f0.w, f1.x, f1.y, f1.z, f1.w};
            #pragma unroll
            for (int j = 0; j < 8; ++j) v[j] = (_Float16)fv[j];
        }
        *(f16x8*)(ws + BIMG_OFF + (size_t)gid * 16) = v;
    } else if (bid < 7696) {                       // ---- i2t init (200704 uint4)
        int gid = (bid - 6912) * 256 + tid;
        uint4 v = make_uint4(0x00800000u, 0x00800000u, 0x00800000u, 0x00800000u);
        ((uint4*)(ws + I2T_OFF))[gid] = v;         // mono(-FLT_MAX)
    } else {                                       // ---- t2i init (1024 uint4)
        uint4 z = make_uint4(0u, 0u, 0u, 0u);
        #pragma unroll
        for (int j = 0; j < 4; ++j)
            ((uint4*)(ws + T2I_OFF))[tid * 4 + j] = z;
    }
}

// gemm: grid 2048 = 32 m-tiles(128) x 64 y; 512 thr (8 waves, 4wm x 2wn,
// wave tile 32x112, acc[2][7]). Single f16 pass. LDS buffer 22528 B
// (A [0,8192) = 128x64, B [8192,22528) = 224x64), double-buffered = 45056
// -> 2 blocks/CU (cross-block overlap hides barrier drain + HBM latency).
// r4-proven 2-barrier loop: STAGE(next) at top, compute cur, __syncthreads
// (compiler drains vmcnt before barrier -> full-chunk prefetch distance).
// LDS slot p holds source k-slot j = (p&3) ^ ((row>>1)&3): DMA dst linear
// (rule #21), swizzle in per-lane global src (m173); reads 2-way = free
// (m136; r8 measured 0 conflicts with this exact scheme).
__global__ __launch_bounds__(512, 4) void gemm_kernel(char* __restrict__ ws) {
    const int bid = blockIdx.x;
    const int swz = (bid & 7) * 256 + (bid >> 3);   // XCD-chunked, bijective (2048%8==0)
    const int mt  = swz & 31;
    const int y   = swz >> 5;
    const int R = *(const int*)(ws + META_OFF);
    const int m_base = mt * 128;
    if (m_base >= R) return;

    const int tid = threadIdx.x;
    const int wid = tid >> 6, lane = tid & 63;
    const int c = lane & 15, g = lane >> 4;
    const int wm = wid >> 1, wn = wid & 1;

    __shared__ __align__(16) unsigned char lds[45056];   // 2 x 22528

    f32x4 acc[2][7];
    #pragma unroll
    for (int m = 0; m < 2; ++m)
        #pragma unroll
        for (int n = 0; n < 7; ++n) acc[m][n] = 0.f;

    const char* Abp = ws + AIMG_OFF + (size_t)m_base * 1536;
    const char* Bbp = ws + BIMG_OFF + (size_t)(y * NPAD) * 1536;

    // per-lane source offsets: LDS pos p -> row = p>>2, k-slot j = (p&3)^((row>>1)&3)
    int a_srcoff, b_srcoff0, b_srcoff1 = 0;
    { int p = tid, row = p >> 2, j = (p & 3) ^ ((row >> 1) & 3);
      a_srcoff  = row * 1536 + j * 16;
      b_srcoff0 = row * 1536 + j * 16; }              // B rows 0..127
    if (tid < 384) {
      int p = 512 + tid, row = p >> 2, j = (p & 3) ^ ((row >> 1) & 3);
      b_srcoff1 = row * 1536 + j * 16; }              // B rows 128..223

    auto STAGE = [&](unsigned char* base, int kc) {
        const int ko = kc * 64;
        async_ld16(Abp + a_srcoff + ko,  base + tid * 16);           // A region
        async_ld16(Bbp + b_srcoff0 + ko, base + 8192 + tid * 16);    // B rows 0-127
        if (tid < 384)
            async_ld16(Bbp + b_srcoff1 + ko, base + 16384 + tid * 16); // B rows 128-223
    };

    // fragment read offsets (swizzled)
    int aof[2], bof[7];
    #pragma unroll
    for (int m = 0; m < 2; ++m) {
        int r = wm * 32 + m * 16 + c;
        aof[m] = r * 64 + ((g ^ ((r >> 1) & 3)) << 4);
    }
    #pragma unroll
    for (int n = 0; n < 7; ++n) {
        int i = wn * 112 + n * 16 + c;
        bof[n] = 8192 + i * 64 + ((g ^ ((i >> 1) & 3)) << 4);
    }

    STAGE(lds, 0);
    __syncthreads();

    #pragma unroll 2
    for (int kc = 0; kc < 24; ++kc) {
        const unsigned char* cb = lds + (kc & 1) * 22528;
        if (kc < 23) STAGE(lds + ((kc + 1) & 1) * 22528, kc + 1);   // full-chunk prefetch
        f16x8 ah[2], bh[7];
        #pragma unroll
        for (int m = 0; m < 2; ++m) ah[m] = *(const f16x8*)(cb + aof[m]);
        #pragma unroll
        for (int n = 0; n < 7; ++n) bh[n] = *(const f16x8*)(cb + bof[n]);
        #pragma unroll
        for (int m = 0; m < 2; ++m)
            #pragma unroll
            for (int n = 0; n < 7; ++n)
                acc[m][n] = __builtin_amdgcn_mfma_f32_16x16x32_f16(ah[m], bh[n], acc[m][n], 0, 0, 0);
        __syncthreads();   // drains staging of next chunk; readers of cur done
    }

    // ---- epilogue (r8-verified, bounds 256->128 / 4->2 / 64->32) ----
    float* rowmax2 = (float*)lds;            // [2][128]
    int*   rowxl   = (int*)(lds + 1024);     // [128]
    const int* rowx = (const int*)(ws + ROWX_OFF);
    if (tid < 128) {
        int gr = m_base + tid;
        rowxl[tid] = (gr < R) ? rowx[gr] : -1;
    }
    // D layout: row = wm*32 + m*16 + g*4 + r ; col = wn*112 + n*16 + c
    #pragma unroll
    for (int m = 0; m < 2; ++m) {
        #pragma unroll
        for (int r = 0; r < 4; ++r) {
            float v = -FLT_MAX;
            #pragma unroll
            for (int n = 0; n < 7; ++n) {
                int nn = wn * 112 + n * 16 + c;
                if (nn < NI) v = fmaxf(v, acc[m][n][r]);
            }
            #pragma unroll
            for (int d = 1; d < 16; d <<= 1) v = fmaxf(v, __shfl_xor(v, d));
            if (c == 0) rowmax2[wn * 128 + wm * 32 + m * 16 + g * 4 + r] = v;
        }
    }
    __syncthreads();
    if (tid < 128) {
        int gr = m_base + tid;
        if (gr < R) {
            float rm = fmaxf(rowmax2[tid], rowmax2[128 + tid]);
            atomicAdd((float*)(ws + T2I_OFF) + rowxl[tid] * 64 + y, rm);
        }
    }
    int xr[2][4];
    #pragma unroll
    for (int m = 0; m < 2; ++m)
        #pragma unroll
        for (int r = 0; r < 4; ++r)
            xr[m][r] = rowxl[wm * 32 + m * 16 + g * 4 + r];

    unsigned* i2t = (unsigned*)(ws + I2T_OFF);
    #pragma unroll
    for (int n = 0; n < 7; ++n) {
        int nn = wn * 112 + n * 16 + c;
        if (nn >= NI) continue;
        int curx = -1; float curm = 0.f;
        #pragma unroll
        for (int m = 0; m < 2; ++m) {
            #pragma unroll
            for (int r = 0; r < 4; ++r) {
                int xv = xr[m][r];
                float v = acc[m][n][r];
                if (xv != curx) {
                    if (curx >= 0)
                        atomicMax(&i2t[(size_t)(curx * 64 + y) * NI + nn], mono_map(curm));
                    curx = xv; curm = v;
                } else {
                    curm = fmaxf(curm, v);
                }
            }
        }
        if (curx >= 0)
            atomicMax(&i2t[(size_t)(curx * 64 + y) * NI + nn], mono_map(curm));
    }
}

// fin: 64 blocks; each wave handles 16 (x,y) pairs; ONE atomicAdd per block.
__global__ __launch_bounds__(256) void fin_kernel(const int* __restrict__ tgt,
                                                  char* __restrict__ ws,
                                                  float* __restrict__ out) {
    const int wid = threadIdx.x >> 6, lane = threadIdx.x & 63;
    float bsum = 0.f;
    for (int rep = 0; rep < 16; ++rep) {
        int w = blockIdx.x * 64 + rep * 4 + wid;
        int x = w >> 6;
        const unsigned* iv = (const unsigned*)(ws + I2T_OFF) + (size_t)w * NI;
        float s = mono_unmap(iv[lane]) + mono_unmap(iv[64 + lane]) + mono_unmap(iv[128 + lane]);
        if (lane < 4) s += mono_unmap(iv[192 + lane]);
        #pragma unroll
        for (int d = 1; d < 64; d <<= 1) s += __shfl_xor(s, d);
        if (lane == 0) {
            float i2tv = s * (1.f / (float)NI);
            float t2is = ((const float*)(ws + T2I_OFF))[w];
            int   nvx  = ((const int*)(ws + NV_OFF))[x];
            float t2iv = t2is / fmaxf((float)nvx, EPS_);
            int tg = tgt[w];
            float mi  = (tg == 1) ? (1.f - i2tv) : fmaxf(i2tv - MARGIN_, 0.f);
            float mtv = (tg == 1) ? (1.f - t2iv) : fmaxf(t2iv - MARGIN_, 0.f);
            bsum += mi + mtv;
        }
    }
    __shared__ float p4[4];
    if (lane == 0) p4[wid] = bsum;
    __syncthreads();
    if (threadIdx.x == 0)
        atomicAdd(out, (p4[0] + p4[1] + p4[2] + p4[3]) * (1.f / 8192.f));
}

// ================= FALLBACK PATH (f32 VALU, known-correct) =================

__global__ __launch_bounds__(64) void prep0_kernel(const int* __restrict__ pm,
                                                   int* __restrict__ wsi,
                                                   float* __restrict__ out) {
    int x = threadIdx.x;
    if (x == 0) out[0] = 0.f;
    if (x >= B_) return;
    const int* row = pm + x * TTXT;
    int lastz = -1;
    for (int t = 0; t < TTXT; ++t) if (row[t] == 0) lastz = t;
    int eos = (lastz >= 0) ? lastz : 0;
    int nv = 0;
    int* vv = wsi + 64 + x * MT;
    for (int t = 1; t < TTXT; ++t) {
        int v = row[t];
        if (t == eos) v = 1;
        if (v == 0) vv[nv++] = t - 1;
    }
    wsi[x] = nv;
}

__global__ __launch_bounds__(256) void sim0_kernel(const float* __restrict__ img,
                                                   const float* __restrict__ txt,
                                                   const int* __restrict__ tgt,
                                                   const int* __restrict__ wsi,
                                                   float* __restrict__ out)
{
    const int bid = blockIdx.x;
    const int x = bid & 63;
    const int y = bid >> 6;
    const int tid = threadIdx.x;
    const int w = tid >> 6;
    const int c = tid & 63;

    __shared__ float sA[MT][DC];
    __shared__ float sB[NI][DC + 4];
    __shared__ float red[4 * 256];
    __shared__ float wred[8];

    const int nv = wsi[x];
    const int* vv = wsi + 64 + x * MT;

    const float* timg = img + (size_t)y * TIMG * DDIM + DDIM;
    const float* ttxt = txt + (size_t)x * TTXT * DDIM + DDIM;

    float acc[16][4];
    #pragma unroll
    for (int v = 0; v < 16; ++v)
        #pragma unroll
        for (int u = 0; u < 4; ++u) acc[v][u] = 0.f;

    for (int dc = 0; dc < DDIM; dc += DC) {
        __syncthreads();
        for (int r = tid; r < NI * 4; r += 256) {
            int row = r >> 2, seg = r & 3;
            float4 vsrc = *reinterpret_cast<const float4*>(
                timg + (size_t)row * DDIM + dc + seg * 4);
            *reinterpret_cast<float4*>(&sB[row][seg * 4]) = vsrc;
        }
        if (tid < nv * 4) {
            int j = tid >> 2, seg = tid & 3;
            int t = vv[j];
            float4 vsrc = *reinterpret_cast<const float4*>(
                ttxt + (size_t)t * DDIM + dc + seg * 4);
            *reinterpret_cast<float4*>(&sA[j][seg * 4]) = vsrc;
        }
        __syncthreads();
        #pragma unroll
        for (int ds = 0; ds < 4; ++ds) {
            float4 b0 = *reinterpret_cast<const float4*>(&sB[c][ds * 4]);
            float4 b1 = *reinterpret_cast<const float4*>(&sB[c + 64][ds * 4]);
            float4 b2 = *reinterpret_cast<const float4*>(&sB[c + 128][ds * 4]);
            float4 b3 = *reinterpret_cast<const float4*>(&sB[(c + 192 < NI) ? (c + 192) : (NI - 1)][ds * 4]);
            #pragma unroll
            for (int v = 0; v < 16; ++v) {
                int t = 4 * v + w;
                if (t < nv) {
                    float4 a = *reinterpret_cast<const float4*>(&sA[t][ds * 4]);
                    acc[v][0] += a.x * b0.x + a.y * b0.y + a.z * b0.z + a.w * b0.w;
                    acc[v][1] += a.x * b1.x + a.y * b1.y + a.z * b1.z + a.w * b1.w;
                    acc[v][2] += a.x * b2.x + a.y * b2.y + a.z * b2.z + a.w * b2.w;
                    acc[v][3] += a.x * b3.x + a.y * b3.y + a.z * b3.z + a.w * b3.w;
                }
            }
        }
    }

    float tsum = 0.f;
    float cmax[4] = {-FLT_MAX, -FLT_MAX, -FLT_MAX, -FLT_MAX};
    #pragma unroll
    for (int v = 0; v < 16; ++v) {
        int t = 4 * v + w;
        if (t < nv) {
            float r = -FLT_MAX;
            #pragma unroll
            for (int u = 0; u < 4; ++u) {
                int i = c + 64 * u;
                if (i < NI) {
                    float val = acc[v][u];
                    r = fmaxf(r, val);
                    cmax[u] = fmaxf(cmax[u], val);
                }
            }
            #pragma unroll
            for (int off = 1; off < 64; off <<= 1)
                r = fmaxf(r, __shfl_xor(r, off));
            tsum += r;
        }
    }

    __syncthreads();
    #pragma unroll
    for (int u = 0; u < 4; ++u)
        red[w * 256 + c + 64 * u] = cmax[u];
    if (c == 0) wred[w] = tsum;
    __syncthreads();

    float cm = 0.f;
    if (tid < NI) {
        float m0 = fmaxf(red[tid], red[256 + tid]);
        float m1 = fmaxf(red[512 + tid], red[768 + tid]);
        cm = fmaxf(m0, m1);
    }
    float s = cm;
    #pragma unroll
    for (int off = 1; off < 64; off <<= 1)
        s += __shfl_xor(s, off);
    if (c == 0) wred[4 + w] = s;
    __syncthreads();

    if (tid == 0) {
        float rowsum = wred[0] + wred[1] + wred[2] + wred[3];
        float colsum = wred[4] + wred[5] + wred[6] + wred[7];
        float t2i = rowsum / fmaxf((float)nv, EPS_);
        float i2t = colsum * (1.f / (float)NI);
        int tg = tgt[x * 64 + y];
        float mi = (tg == 1) ? (1.f - i2t) : fmaxf(i2t - MARGIN_, 0.f);
        float mt = (tg == 1) ? (1.f - t2i) : fmaxf(t2i - MARGIN_, 0.f);
        atomicAdd(out, (mi + mt) * (1.f / 8192.f));
    }
}

// ================= launcher =================

extern "C" void kernel_launch(void* const* d_in, const int* in_sizes, int n_in,
                              void* d_out, int out_size, void* d_ws, size_t ws_size,
                              hipStream_t stream) {
    const float* img = (const float*)d_in[0];
    const float* txt = (const float*)d_in[1];
    const int*   pm  = (const int*)d_in[2];
    const int*   tgt = (const int*)d_in[3];
    float* out = (float*)d_out;

    if (ws_size >= (size_t)WS_NEEDED) {
        char* wsc = (char*)d_ws;
        hipLaunchKernelGGL(prep_kernel, dim3(1),    dim3(64),  0, stream, pm, wsc, out);
        hipLaunchKernelGGL(conv_kernel, dim3(7697), dim3(256), 0, stream, img, txt, wsc);
        hipLaunchKernelGGL(gemm_kernel, dim3(2048), dim3(512), 0, stream, wsc);
        hipLaunchKernelGGL(fin_kernel,  dim3(64),   dim3(256), 0, stream, tgt, wsc, out);
    } else {
        int* wsi = (int*)d_ws;
        hipLaunchKernelGGL(prep0_kernel, dim3(1),    dim3(64),  0, stream, pm, wsi, out);
        hipLaunchKernelGGL(sim0_kernel,  dim3(4096), dim3(256), 0, stream,
                           img, txt, tgt, wsi, out);
    }
}